// Round 2
// baseline (6357.776 us; speedup 1.0000x reference)
//
#include <hip/hip_runtime.h>
#include <hip/hip_bf16.h>
#include <hip/hip_fp16.h>
#include <stdint.h>

// Problem dims
#define BB 128
#define TT 512
#define HH 256
#define VV 29
#define NSTEP 63
#define BT (BB*TT)
#define CHUNK 64   // layer-1 time chunk

typedef _Float16 f16;
typedef _Float16 f16x2 __attribute__((ext_vector_type(2)));
typedef _Float16 f16x8 __attribute__((ext_vector_type(8)));
typedef float f32x4 __attribute__((ext_vector_type(4)));

static __device__ __forceinline__ float fdot2u(uint32_t a, uint32_t b, float c) {
  return __builtin_amdgcn_fdot2(__builtin_bit_cast(f16x2, a),
                                __builtin_bit_cast(f16x2, b), c, false);
}
static __device__ __forceinline__ float sigm_(float x) {
  return 1.0f / (1.0f + __expf(-x));
}

// ---------------- fp32 -> f16 convert ----------------
__global__ void k_cvt(const float* __restrict__ s, f16* __restrict__ d, int n) {
  int i = blockIdx.x * 256 + threadIdx.x;
  if (i < n) d[i] = (f16)s[i];
}

// ---------------- persistent GRU scan: 1 WG per (batch, dir) ----------------
// Whh (f16) held in VGPRs: thread=(pair=unit, half=k-half); 3 half-rows x 64 half2.
// h carried across launches in hstate (f32, (2,B,256)).
template<int LAYER>
__global__ __launch_bounds__(512, 2)
void k_scan(const float* __restrict__ x,        // L0: (B,T,2)
            const f16* __restrict__ gi,         // L1: (B,nsteps,1536) chunk-local
            const uint32_t* __restrict__ whh,   // (2,768,128) as half2
            const float* __restrict__ wih0,     // L0: (2,768,2)
            const float* __restrict__ bih,      // L0: (2,768)
            const float* __restrict__ bhh,      // (2,768)
            f16* __restrict__ y,                // (B,T,512) [t][dir*256+p]
            float* __restrict__ hstate,         // (2,B,256) f32
            int t0, int nsteps)
{
  const int wg = blockIdx.x, b = wg >> 1, dir = wg & 1;
  const int tid = threadIdx.x, pair = tid >> 1, half = tid & 1;
  __shared__ uint32_t hv[128];   // h as half2
  __shared__ float ysh[256];

  uint32_t w0[64], w1[64], w2[64];
  {
    const uint32_t* wp = whh + (size_t)dir * 768 * 128;
    const uint32_t* r0 = wp + (size_t)pair * 128 + half * 64;
    const uint32_t* r1 = wp + (size_t)(pair + 256) * 128 + half * 64;
    const uint32_t* r2 = wp + (size_t)(pair + 512) * 128 + half * 64;
#pragma unroll
    for (int i = 0; i < 64; i++) { w0[i] = r0[i]; w1[i] = r1[i]; w2[i] = r2[i]; }
  }
  const float bh0 = bhh[dir * 768 + pair];
  const float bh1 = bhh[dir * 768 + pair + 256];
  const float bh2 = bhh[dir * 768 + pair + 512];
  float bi0 = 0, bi1 = 0, bi2 = 0;
  float wi00 = 0, wi01 = 0, wi10 = 0, wi11 = 0, wi20 = 0, wi21 = 0;
  if (LAYER == 0) {
    bi0 = bih[dir * 768 + pair];
    bi1 = bih[dir * 768 + pair + 256];
    bi2 = bih[dir * 768 + pair + 512];
    wi00 = wih0[(dir * 768 + pair) * 2 + 0];
    wi01 = wih0[(dir * 768 + pair) * 2 + 1];
    wi10 = wih0[(dir * 768 + pair + 256) * 2 + 0];
    wi11 = wih0[(dir * 768 + pair + 256) * 2 + 1];
    wi20 = wih0[(dir * 768 + pair + 512) * 2 + 0];
    wi21 = wih0[(dir * 768 + pair + 512) * 2 + 1];
  }
  float* hs = hstate + ((size_t)dir * BB + b) * 256;
  float hreg = hs[pair];
  if (tid < 128) {
    f16x2 p2; p2[0] = (f16)hs[2 * tid]; p2[1] = (f16)hs[2 * tid + 1];
    hv[tid] = __builtin_bit_cast(uint32_t, p2);
  }
  __syncthreads();

  for (int s = 0; s < nsteps; ++s) {
    const int t = dir ? (TT - 1 - t0 - s) : (t0 + s);
    float a0 = 0.f, a1 = 0.f, a2 = 0.f;
#pragma unroll
    for (int i = 0; i < 64; i++) {
      uint32_t hh = hv[half * 64 + i];
      a0 = fdot2u(w0[i], hh, a0);
      a1 = fdot2u(w1[i], hh, a1);
      a2 = fdot2u(w2[i], hh, a2);
    }
    a0 += __shfl_xor(a0, 1);
    a1 += __shfl_xor(a1, 1);
    a2 += __shfl_xor(a2, 1);

    float gr, gz, gn;
    if (LAYER == 0) {
      float x0 = x[((size_t)b * TT + t) * 2 + 0];
      float x1 = x[((size_t)b * TT + t) * 2 + 1];
      gr = wi00 * x0 + wi01 * x1 + bi0;
      gz = wi10 * x0 + wi11 * x1 + bi1;
      gn = wi20 * x0 + wi21 * x1 + bi2;
    } else {
      const f16* g = gi + ((size_t)b * nsteps + s) * 1536 + dir * 768 + pair;
      gr = (float)g[0]; gz = (float)g[256]; gn = (float)g[512];
    }
    float r = sigm_(gr + a0 + bh0);
    float z = sigm_(gz + a1 + bh1);
    float n = tanhf(gn + r * (a2 + bh2));
    float hn = (1.0f - z) * n + z * hreg;
    hreg = hn;
    __syncthreads();  // all hv reads done
    if (half == 0) { ((f16*)hv)[pair] = (f16)hn; ysh[pair] = hn; }
    __syncthreads();  // hv/ysh updated
    if (tid < 256) y[((size_t)b * TT + t) * 512 + dir * 256 + tid] = (f16)ysh[tid];
  }
  if (half == 0) hs[pair] = hreg;
}

// ---------------- f16 MFMA GEMM: C = Arows @ Bt^T + bias ---------------------
// 64x64 tile, 256 threads (4 waves). Row r of A lives at
//   A + (r>>shift)*bstride + (r&mask)*inner      (inner may be negative)
// C store: C[row*ldc + coloff + col]. All dims multiples of tile.
__global__ __launch_bounds__(256)
void k_gemm(const f16* __restrict__ A, const f16* __restrict__ Bt,
            f16* __restrict__ C, const float* __restrict__ bias,
            int K, int shift, long bstride, int inner, int ldc, int coloff)
{
  const int m0 = blockIdx.x * 64, n0 = blockIdx.y * 64;
  const int tid = threadIdx.x, lane = tid & 63, wv = tid >> 6;
  __shared__ __align__(16) f16 As[64 * 40];
  __shared__ __align__(16) f16 Bs[64 * 40];
  f32x4 acc[4] = {{0,0,0,0},{0,0,0,0},{0,0,0,0},{0,0,0,0}};
  const int lrow = tid >> 2, lseg = tid & 3;
  const int ml = lane & 15, quad = lane >> 4;
  const int r = m0 + lrow;
  const f16* arow = A + (long)(r >> shift) * bstride
                      + (long)(r & ((1 << shift) - 1)) * inner;
  const f16* brow = Bt + (size_t)(n0 + lrow) * K;
  for (int k0 = 0; k0 < K; k0 += 32) {
    uint4 av = *(const uint4*)(arow + k0 + lseg * 8);
    uint4 bv = *(const uint4*)(brow + k0 + lseg * 8);
    __syncthreads();
    *(uint4*)(As + lrow * 40 + lseg * 8) = av;
    *(uint4*)(Bs + lrow * 40 + lseg * 8) = bv;
    __syncthreads();
    f16x8 af = *(const f16x8*)(As + (wv * 16 + ml) * 40 + quad * 8);
#pragma unroll
    for (int ns = 0; ns < 4; ++ns) {
      f16x8 bf = *(const f16x8*)(Bs + (ns * 16 + ml) * 40 + quad * 8);
      acc[ns] = __builtin_amdgcn_mfma_f32_16x16x32_f16(af, bf, acc[ns], 0, 0, 0);
    }
  }
#pragma unroll
  for (int ns = 0; ns < 4; ++ns) {
#pragma unroll
    for (int rr = 0; rr < 4; ++rr) {
      int row = m0 + wv * 16 + quad * 4 + rr;
      int col = n0 + ns * 16 + ml;
      float v = acc[ns][rr];
      if (bias) v += bias[col];
      C[(size_t)row * ldc + coloff + col] = (f16)v;
    }
  }
}

// ---------------- decoder init ----------------
__global__ void k_dinit(const float* __restrict__ hf0, const float* __restrict__ hf1,
                        const int* __restrict__ tseq,
                        f16* __restrict__ h0, f16* __restrict__ h1, int* __restrict__ tok) {
  int i = blockIdx.x * 256 + threadIdx.x;  // 32768
  h0[i] = (f16)(hf0[i] + hf0[32768 + i]);
  h1[i] = (f16)(hf1[i] + hf1[32768 + i]);
  if (i < BB) tok[i] = tseq[i * 64];
}

// ---------------- decoder cell gate kernels ----------------
__global__ __launch_bounds__(256)
void k_gates0(const f16* __restrict__ wih0,   // (768,8)
              const float* __restrict__ bih0, // 768
              const float* __restrict__ emb,  // (29,8) fp32
              const int* __restrict__ tok,
              const f16* __restrict__ G,      // (B,768) gh incl bhh
              const f16* __restrict__ hprev, f16* __restrict__ hnew) {
  int b = blockIdx.x, p = threadIdx.x;
  __shared__ float e[8];
  if (p < 8) e[p] = emb[tok[b] * 8 + p];
  __syncthreads();
  float gr = bih0[p], gz = bih0[p + 256], gn = bih0[p + 512];
#pragma unroll
  for (int i = 0; i < 8; i++) {
    gr += e[i] * (float)wih0[p * 8 + i];
    gz += e[i] * (float)wih0[(p + 256) * 8 + i];
    gn += e[i] * (float)wih0[(p + 512) * 8 + i];
  }
  const f16* g = G + b * 768;
  float r = sigm_(gr + (float)g[p]);
  float z = sigm_(gz + (float)g[p + 256]);
  float n = tanhf(gn + r * (float)g[p + 512]);
  float hp = (float)hprev[b * 256 + p];
  hnew[b * 256 + p] = (f16)((1.f - z) * n + z * hp);
}

__global__ __launch_bounds__(256)
void k_gates1(const f16* __restrict__ Ga, const f16* __restrict__ Gb,
              const f16* __restrict__ hprev, f16* __restrict__ hnew) {
  int b = blockIdx.x, p = threadIdx.x;
  const f16* ga = Ga + b * 768;
  const f16* gb = Gb + b * 768;
  float r = sigm_((float)ga[p] + (float)gb[p]);
  float z = sigm_((float)ga[p + 256] + (float)gb[p + 256]);
  float n = tanhf((float)ga[p + 512] + r * (float)gb[p + 512]);
  float hp = (float)hprev[b * 256 + p];
  hnew[b * 256 + p] = (f16)((1.f - z) * n + z * hp);
}

// ---------------- fused attention + output + argmax, 1 WG per batch ----------
// scores[b,t] = enc[b,t,:] . q[b,:]   (q = h1 @ qW^T + qb, computed by k_gemm)
__global__ __launch_bounds__(256)
void k_attn(const f16* __restrict__ enc,      // (B,T,256)
            const f16* __restrict__ q,        // (B,256)
            const f16* __restrict__ h1,       // (B,256)
            const f16* __restrict__ outw,     // (29,256)
            const float* __restrict__ outb,   // 29
            float* __restrict__ dlogits, int* __restrict__ tok, int step) {
  int b = blockIdx.x, tid = threadIdx.x;
  __shared__ uint32_t qs[128];
  __shared__ float sc[512];
  __shared__ float red[4];
  __shared__ float hc[256];
  __shared__ float lg[32];
  if (tid < 128) qs[tid] = ((const uint32_t*)q)[b * 128 + tid];
  __syncthreads();
#pragma unroll
  for (int pass = 0; pass < 2; ++pass) {
    int t = tid + pass * 256;
    const uint4* ep = (const uint4*)(enc + ((size_t)b * TT + t) * 256);
    float s = 0.f;
#pragma unroll
    for (int j = 0; j < 32; j++) {
      uint4 v = ep[j];
      s = fdot2u(v.x, qs[j * 4 + 0], s);
      s = fdot2u(v.y, qs[j * 4 + 1], s);
      s = fdot2u(v.z, qs[j * 4 + 2], s);
      s = fdot2u(v.w, qs[j * 4 + 3], s);
    }
    sc[t] = s;
  }
  __syncthreads();
  float mloc = fmaxf(sc[tid], sc[tid + 256]);
#pragma unroll
  for (int off = 32; off; off >>= 1) mloc = fmaxf(mloc, __shfl_xor(mloc, off));
  if ((tid & 63) == 0) red[tid >> 6] = mloc;
  __syncthreads();
  float m = fmaxf(fmaxf(red[0], red[1]), fmaxf(red[2], red[3]));
  float e0 = __expf(sc[tid] - m), e1 = __expf(sc[tid + 256] - m);
  __syncthreads();  // red/sc reads done before reuse
  sc[tid] = e0; sc[tid + 256] = e1;
  float lloc = e0 + e1;
#pragma unroll
  for (int off = 32; off; off >>= 1) lloc += __shfl_xor(lloc, off);
  if ((tid & 63) == 0) red[tid >> 6] = lloc;
  __syncthreads();
  float l = red[0] + red[1] + red[2] + red[3];
  float ctx = 0.f;
#pragma unroll 4
  for (int t = 0; t < TT; t++) ctx += sc[t] * (float)enc[((size_t)b * TT + t) * 256 + tid];
  ctx /= l;
  hc[tid] = ctx + (float)h1[b * 256 + tid];
  __syncthreads();
  if (tid < VV) {
    float acc = outb[tid];
    const f16* ow = outw + tid * 256;
    for (int k = 0; k < 256; k++) acc += hc[k] * (float)ow[k];
    lg[tid] = acc;
    dlogits[((size_t)b * NSTEP + step) * VV + tid] = acc;
  }
  __syncthreads();
  if (tid == 0) {
    int best = 0; float bv = lg[0];
    for (int v = 1; v < VV; ++v) if (lg[v] > bv) { bv = lg[v]; best = v; }
    tok[b] = best;
  }
}

// ---------------- final hidden copy ----------------
__global__ void k_fin(const f16* __restrict__ h0, const f16* __restrict__ h1,
                      float* __restrict__ out) {
  int i = blockIdx.x * 256 + threadIdx.x;  // 65536
  out[233856 + i] = (float)(i < 32768 ? h0[i] : h1[i - 32768]);
}

extern "C" void kernel_launch(void* const* d_in, const int* in_sizes, int n_in,
                              void* d_out, int out_size, void* d_ws, size_t ws_size,
                              hipStream_t stream) {
  (void)in_sizes; (void)n_in; (void)out_size; (void)ws_size;
  const float* x     = (const float*)d_in[0];
  const int*   tseq  = (const int*)d_in[1];
  const float* eWih0 = (const float*)d_in[2];
  const float* eWhh0 = (const float*)d_in[3];
  const float* ebih0 = (const float*)d_in[4];
  const float* ebhh0 = (const float*)d_in[5];
  const float* eWih1 = (const float*)d_in[6];
  const float* eWhh1 = (const float*)d_in[7];
  const float* ebih1 = (const float*)d_in[8];
  const float* ebhh1 = (const float*)d_in[9];
  const float* e2dW  = (const float*)d_in[10];
  const float* e2db  = (const float*)d_in[11];
  const float* dWih0 = (const float*)d_in[12];
  const float* dWih1 = (const float*)d_in[13];
  const float* dWhh  = (const float*)d_in[14];
  const float* dbih  = (const float*)d_in[15];
  const float* dbhh  = (const float*)d_in[16];
  const float* qW    = (const float*)d_in[17];
  const float* qb    = (const float*)d_in[18];
  const float* outW  = (const float*)d_in[19];
  const float* outb  = (const float*)d_in[20];
  const float* emb   = (const float*)d_in[21];

  // ---- workspace ledger (peak ~166 MB) ----
  uint8_t* ws = (uint8_t*)d_ws;
  size_t o = 0;
  auto take = [&](size_t bytes) -> void* {
    void* p = ws + o;
    o += (bytes + 255) & ~(size_t)255;
    return p;
  };
  f16* whh0_16  = (f16*)take((size_t)2 * 768 * 256 * 2);
  f16* whh1_16  = (f16*)take((size_t)2 * 768 * 256 * 2);
  f16* wih1_16  = (f16*)take((size_t)2 * 768 * 512 * 2);
  f16* e2d_16   = (f16*)take((size_t)256 * 512 * 2);
  f16* qw_16    = (f16*)take((size_t)256 * 256 * 2);
  f16* outw_16  = (f16*)take((size_t)29 * 256 * 2);
  f16* dwih0_16 = (f16*)take((size_t)768 * 8 * 2);
  f16* dwih1_16 = (f16*)take((size_t)768 * 256 * 2);
  f16* dwhh_16  = (f16*)take((size_t)2 * 768 * 256 * 2);
  f16* y0   = (f16*)take((size_t)BT * 512 * 2);        // 67.1 MB; enc aliases it later
  f16* y1   = (f16*)take((size_t)BT * 512 * 2);        // 67.1 MB
  f16* gi   = (f16*)take((size_t)BB * CHUNK * 1536 * 2); // 25.2 MB rolling chunk
  float* hs0 = (float*)take((size_t)2 * BB * 256 * 4);
  float* hs1 = (float*)take((size_t)2 * BB * 256 * 4);
  f16* qbuf = (f16*)take((size_t)BB * 256 * 2);
  f16* h0buf[2] = { (f16*)take((size_t)BB * 256 * 2), (f16*)take((size_t)BB * 256 * 2) };
  f16* h1buf[2] = { (f16*)take((size_t)BB * 256 * 2), (f16*)take((size_t)BB * 256 * 2) };
  f16* G0  = (f16*)take((size_t)BB * 768 * 2);
  f16* G1a = (f16*)take((size_t)BB * 768 * 2);
  f16* G1b = (f16*)take((size_t)BB * 768 * 2);
  int* tok = (int*)take((size_t)BB * 4);
  f16* enc = y0;  // alias: y0 dead once the last gi chunk GEMM has run

  hipMemsetAsync(hs0, 0, (size_t)2 * BB * 256 * 4, stream);
  hipMemsetAsync(hs1, 0, (size_t)2 * BB * 256 * 4, stream);

  auto cvt = [&](const float* s, f16* d, int n) {
    k_cvt<<<(n + 255) / 256, 256, 0, stream>>>(s, d, n);
  };
  cvt(eWhh0, whh0_16, 2 * 768 * 256);
  cvt(eWhh1, whh1_16, 2 * 768 * 256);
  cvt(eWih1, wih1_16, 2 * 768 * 512);
  cvt(e2dW,  e2d_16,  256 * 512);
  cvt(qW,    qw_16,   256 * 256);
  cvt(outW,  outw_16, 29 * 256);
  cvt(dWih0, dwih0_16, 768 * 8);
  cvt(dWih1, dwih1_16, 768 * 256);
  cvt(dWhh,  dwhh_16, 2 * 768 * 256);

  // encoder layer 0 (both dirs, full T; gi inline since IN=2)
  k_scan<0><<<256, 512, 0, stream>>>(x, nullptr, (const uint32_t*)whh0_16,
                                     eWih0, ebih0, ebhh0, y0, hs0, 0, TT);

  // encoder layer 1: time-chunked gi GEMM + scan
  const long BSTR = (long)TT * 512;  // per-b element stride in y0
  for (int c = 0; c < TT / CHUNK; ++c) {
    const int t0 = c * CHUNK;
    // fwd dir gi: rows (b,s) <- y0[b, t0+s]
    k_gemm<<<dim3(BB * CHUNK / 64, 12), 256, 0, stream>>>(
        y0 + (size_t)t0 * 512, wih1_16, gi, ebih1,
        512, 6, BSTR, 512, 1536, 0);
    // bwd dir gi: rows (b,s) <- y0[b, (TT-1-t0)-s]
    k_gemm<<<dim3(BB * CHUNK / 64, 12), 256, 0, stream>>>(
        y0 + (size_t)(TT - 1 - t0) * 512, wih1_16 + (size_t)768 * 512, gi, ebih1 + 768,
        512, 6, BSTR, -512, 1536, 768);
    k_scan<1><<<256, 512, 0, stream>>>(nullptr, gi, (const uint32_t*)whh1_16,
                                       nullptr, nullptr, ebhh1, y1, hs1, t0, CHUNK);
  }

  // enc = y1 @ e2d^T + b   (writes into y0's region)
  k_gemm<<<dim3(BT / 64, 4), 256, 0, stream>>>(y1, e2d_16, enc, e2db,
                                               512, 30, 0, 512, 256, 0);
  k_dinit<<<128, 256, 0, stream>>>(hs0, hs1, tseq, h0buf[0], h1buf[0], tok);

  int cur = 0;
  for (int s = 0; s < NSTEP; ++s) {
    int nxt = cur ^ 1;
    // cell0: gh = h0 @ dWhh0^T + dbhh0
    k_gemm<<<dim3(2, 12), 256, 0, stream>>>(h0buf[cur], dwhh_16, G0, dbhh,
                                            256, 30, 0, 256, 768, 0);
    k_gates0<<<128, 256, 0, stream>>>(dwih0_16, dbih, emb, tok, G0,
                                      h0buf[cur], h0buf[nxt]);
    // cell1: gi = h0' @ dWih1^T + dbih1 ; gh = h1 @ dWhh1^T + dbhh1
    k_gemm<<<dim3(2, 12), 256, 0, stream>>>(h0buf[nxt], dwih1_16, G1a, dbih + 768,
                                            256, 30, 0, 256, 768, 0);
    k_gemm<<<dim3(2, 12), 256, 0, stream>>>(h1buf[cur], dwhh_16 + (size_t)768 * 256,
                                            G1b, dbhh + 768, 256, 30, 0, 256, 768, 0);
    k_gates1<<<128, 256, 0, stream>>>(G1a, G1b, h1buf[cur], h1buf[nxt]);
    // q = h1' @ qW^T + qb
    k_gemm<<<dim3(2, 4), 256, 0, stream>>>(h1buf[nxt], qw_16, qbuf, qb,
                                           256, 30, 0, 256, 256, 0);
    // attention + logits + argmax
    k_attn<<<128, 256, 0, stream>>>(enc, qbuf, h1buf[nxt], outw_16, outb,
                                    (float*)d_out, tok, s);
    cur = nxt;
  }
  k_fin<<<256, 256, 0, stream>>>(h0buf[cur], h1buf[cur], (float*)d_out);
}

// Round 3
// 5570.975 us; speedup vs baseline: 1.1412x; 1.1412x over previous
//
#include <hip/hip_runtime.h>
#include <hip/hip_bf16.h>
#include <hip/hip_fp16.h>
#include <stdint.h>

// Problem dims
#define BB 128
#define TT 512
#define HH 256
#define VV 29
#define NSTEP 63
#define BT (BB*TT)
#define CHUNK 64   // layer-1 time chunk

typedef _Float16 f16;
typedef _Float16 f16x2 __attribute__((ext_vector_type(2)));
typedef _Float16 f16x8 __attribute__((ext_vector_type(8)));
typedef float f32x4 __attribute__((ext_vector_type(4)));

static __device__ __forceinline__ float fdot2u(uint32_t a, uint32_t b, float c) {
  return __builtin_amdgcn_fdot2(__builtin_bit_cast(f16x2, a),
                                __builtin_bit_cast(f16x2, b), c, false);
}
static __device__ __forceinline__ float sigm_(float x) {
  return 1.0f / (1.0f + __expf(-x));
}

// ---------------- fp32 -> f16 convert ----------------
__global__ void k_cvt(const float* __restrict__ s, f16* __restrict__ d, int n) {
  int i = blockIdx.x * 256 + threadIdx.x;
  if (i < n) d[i] = (f16)s[i];
}

// ---------------- persistent GRU scan: 1 WG per (batch, dir) ----------------
// Whh (f16) in VGPRs as uint4[16] x3. h in LDS as uint4[32] -> b128 broadcasts.
template<int LAYER>
__global__ __launch_bounds__(512, 2)
void k_scan(const float* __restrict__ x,        // L0: (B,T,2)
            const f16* __restrict__ gi,         // L1: (B,nsteps,1536) chunk-local
            const uint32_t* __restrict__ whh,   // (2,768,128) as half2
            const float* __restrict__ wih0,     // L0: (2,768,2)
            const float* __restrict__ bih,      // L0: (2,768)
            const float* __restrict__ bhh,      // (2,768)
            f16* __restrict__ y,                // (B,T,512) [t][dir*256+p]
            float* __restrict__ hstate,         // (2,B,256) f32
            int t0, int nsteps)
{
  const int wg = blockIdx.x, b = wg >> 1, dir = wg & 1;
  const int tid = threadIdx.x, pair = tid >> 1, half = tid & 1;
  __shared__ __align__(16) uint4 hv4[32];   // h as f16[256]

  uint4 w0[16], w1[16], w2[16];
  {
    const uint32_t* wp = whh + (size_t)dir * 768 * 128;
    const uint4* r0 = (const uint4*)(wp + (size_t)pair * 128 + half * 64);
    const uint4* r1 = (const uint4*)(wp + (size_t)(pair + 256) * 128 + half * 64);
    const uint4* r2 = (const uint4*)(wp + (size_t)(pair + 512) * 128 + half * 64);
#pragma unroll
    for (int i = 0; i < 16; i++) { w0[i] = r0[i]; w1[i] = r1[i]; w2[i] = r2[i]; }
  }
  const float bh0 = bhh[dir * 768 + pair];
  const float bh1 = bhh[dir * 768 + pair + 256];
  const float bh2 = bhh[dir * 768 + pair + 512];
  float bi0 = 0, bi1 = 0, bi2 = 0;
  float wi00 = 0, wi01 = 0, wi10 = 0, wi11 = 0, wi20 = 0, wi21 = 0;
  if (LAYER == 0) {
    bi0 = bih[dir * 768 + pair];
    bi1 = bih[dir * 768 + pair + 256];
    bi2 = bih[dir * 768 + pair + 512];
    wi00 = wih0[(dir * 768 + pair) * 2 + 0];
    wi01 = wih0[(dir * 768 + pair) * 2 + 1];
    wi10 = wih0[(dir * 768 + pair + 256) * 2 + 0];
    wi11 = wih0[(dir * 768 + pair + 256) * 2 + 1];
    wi20 = wih0[(dir * 768 + pair + 512) * 2 + 0];
    wi21 = wih0[(dir * 768 + pair + 512) * 2 + 1];
  }
  float* hs = hstate + ((size_t)dir * BB + b) * 256;
  float hreg = hs[pair];
  if (tid < 128) {
    f16x2 p2; p2[0] = (f16)hs[2 * tid]; p2[1] = (f16)hs[2 * tid + 1];
    ((uint32_t*)hv4)[tid] = __builtin_bit_cast(uint32_t, p2);
  }
  __syncthreads();

  const uint4* hw = hv4 + half * 16;
  for (int s = 0; s < nsteps; ++s) {
    const int t = dir ? (TT - 1 - t0 - s) : (t0 + s);
    // issue input loads first; latency hides under the dot loop
    float gr, gz, gn;
    if (LAYER == 0) {
      float x0 = x[((size_t)b * TT + t) * 2 + 0];
      float x1 = x[((size_t)b * TT + t) * 2 + 1];
      gr = wi00 * x0 + wi01 * x1 + bi0;
      gz = wi10 * x0 + wi11 * x1 + bi1;
      gn = wi20 * x0 + wi21 * x1 + bi2;
    } else {
      const f16* g = gi + ((size_t)b * nsteps + s) * 1536 + dir * 768 + pair;
      gr = (float)g[0]; gz = (float)g[256]; gn = (float)g[512];
    }
    float a0 = 0.f, a1 = 0.f, a2 = 0.f;
#pragma unroll
    for (int j = 0; j < 16; ++j) {
      uint4 hh = hw[j];
      a0 = fdot2u(w0[j].x, hh.x, a0); a0 = fdot2u(w0[j].y, hh.y, a0);
      a0 = fdot2u(w0[j].z, hh.z, a0); a0 = fdot2u(w0[j].w, hh.w, a0);
      a1 = fdot2u(w1[j].x, hh.x, a1); a1 = fdot2u(w1[j].y, hh.y, a1);
      a1 = fdot2u(w1[j].z, hh.z, a1); a1 = fdot2u(w1[j].w, hh.w, a1);
      a2 = fdot2u(w2[j].x, hh.x, a2); a2 = fdot2u(w2[j].y, hh.y, a2);
      a2 = fdot2u(w2[j].z, hh.z, a2); a2 = fdot2u(w2[j].w, hh.w, a2);
    }
    a0 += __shfl_xor(a0, 1);
    a1 += __shfl_xor(a1, 1);
    a2 += __shfl_xor(a2, 1);

    float r = sigm_(gr + a0 + bh0);
    float z = sigm_(gz + a1 + bh1);
    float n = tanhf(gn + r * (a2 + bh2));
    float hn = (1.0f - z) * n + z * hreg;
    hreg = hn;
    if (half == 0) y[((size_t)b * TT + t) * 512 + dir * 256 + pair] = (f16)hn;
    __syncthreads();  // all hv reads done
    if (half == 0) ((f16*)hv4)[pair] = (f16)hn;
    __syncthreads();  // hv updated
  }
  if (half == 0) hs[pair] = hreg;
}

// ---------------- f16 MFMA GEMM: C = Arows @ Bt^T + bias ---------------------
// 64x64 tile, 256 threads (4 waves). Row r of A lives at
//   A + (r>>shift)*bstride + (r&mask)*inner      (inner may be negative)
__global__ __launch_bounds__(256)
void k_gemm(const f16* __restrict__ A, const f16* __restrict__ Bt,
            f16* __restrict__ C, const float* __restrict__ bias,
            int K, int shift, long bstride, int inner, int ldc, int coloff)
{
  const int m0 = blockIdx.x * 64, n0 = blockIdx.y * 64;
  const int tid = threadIdx.x, lane = tid & 63, wv = tid >> 6;
  __shared__ __align__(16) f16 As[64 * 40];
  __shared__ __align__(16) f16 Bs[64 * 40];
  f32x4 acc[4] = {{0,0,0,0},{0,0,0,0},{0,0,0,0},{0,0,0,0}};
  const int lrow = tid >> 2, lseg = tid & 3;
  const int ml = lane & 15, quad = lane >> 4;
  const int r = m0 + lrow;
  const f16* arow = A + (long)(r >> shift) * bstride
                      + (long)(r & ((1 << shift) - 1)) * inner;
  const f16* brow = Bt + (size_t)(n0 + lrow) * K;
  for (int k0 = 0; k0 < K; k0 += 32) {
    uint4 av = *(const uint4*)(arow + k0 + lseg * 8);
    uint4 bv = *(const uint4*)(brow + k0 + lseg * 8);
    __syncthreads();
    *(uint4*)(As + lrow * 40 + lseg * 8) = av;
    *(uint4*)(Bs + lrow * 40 + lseg * 8) = bv;
    __syncthreads();
    f16x8 af = *(const f16x8*)(As + (wv * 16 + ml) * 40 + quad * 8);
#pragma unroll
    for (int ns = 0; ns < 4; ++ns) {
      f16x8 bf = *(const f16x8*)(Bs + (ns * 16 + ml) * 40 + quad * 8);
      acc[ns] = __builtin_amdgcn_mfma_f32_16x16x32_f16(af, bf, acc[ns], 0, 0, 0);
    }
  }
#pragma unroll
  for (int ns = 0; ns < 4; ++ns) {
#pragma unroll
    for (int rr = 0; rr < 4; ++rr) {
      int row = m0 + wv * 16 + quad * 4 + rr;
      int col = n0 + ns * 16 + ml;
      float v = acc[ns][rr];
      if (bias) v += bias[col];
      C[(size_t)row * ldc + coloff + col] = (f16)v;
    }
  }
}

// ---------------- persistent decoder: 1 WG per batch, all 63 steps -----------
// 3-row matvec: rows (row0, row0+256, row0+512) of W (f16, ld=256) dot h (LDS)
static __device__ __forceinline__ void mv3(const f16* __restrict__ W, int row0,
                                           const uint4* __restrict__ hsh,
                                           float& g0, float& g1, float& g2) {
  const uint4* w0 = (const uint4*)(W + (size_t)row0 * 256);
  const uint4* w1 = (const uint4*)(W + (size_t)(row0 + 256) * 256);
  const uint4* w2 = (const uint4*)(W + (size_t)(row0 + 512) * 256);
#pragma unroll 2
  for (int kc = 0; kc < 8; ++kc) {
    uint4 hq[4], aq[4], bq[4], cq[4];
#pragma unroll
    for (int j = 0; j < 4; ++j) {
      aq[j] = w0[4 * kc + j]; bq[j] = w1[4 * kc + j]; cq[j] = w2[4 * kc + j];
      hq[j] = hsh[4 * kc + j];
    }
#pragma unroll
    for (int j = 0; j < 4; ++j) {
      g0 = fdot2u(aq[j].x, hq[j].x, g0); g0 = fdot2u(aq[j].y, hq[j].y, g0);
      g0 = fdot2u(aq[j].z, hq[j].z, g0); g0 = fdot2u(aq[j].w, hq[j].w, g0);
      g1 = fdot2u(bq[j].x, hq[j].x, g1); g1 = fdot2u(bq[j].y, hq[j].y, g1);
      g1 = fdot2u(bq[j].z, hq[j].z, g1); g1 = fdot2u(bq[j].w, hq[j].w, g1);
      g2 = fdot2u(cq[j].x, hq[j].x, g2); g2 = fdot2u(cq[j].y, hq[j].y, g2);
      g2 = fdot2u(cq[j].z, hq[j].z, g2); g2 = fdot2u(cq[j].w, hq[j].w, g2);
    }
  }
}
// 1-row dot: W row (256 f16) dot h (LDS)
static __device__ __forceinline__ float mv1(const f16* __restrict__ W, long row,
                                            const uint4* __restrict__ hsh, float g) {
  const uint4* w = (const uint4*)(W + (size_t)row * 256);
#pragma unroll 2
  for (int kc = 0; kc < 8; ++kc) {
    uint4 aq[4], hq[4];
#pragma unroll
    for (int j = 0; j < 4; ++j) { aq[j] = w[4 * kc + j]; hq[j] = hsh[4 * kc + j]; }
#pragma unroll
    for (int j = 0; j < 4; ++j) {
      g = fdot2u(aq[j].x, hq[j].x, g); g = fdot2u(aq[j].y, hq[j].y, g);
      g = fdot2u(aq[j].z, hq[j].z, g); g = fdot2u(aq[j].w, hq[j].w, g);
    }
  }
  return g;
}
static __device__ __forceinline__ float edot(uint4 w, const float* e) {
  f16x2 a = __builtin_bit_cast(f16x2, w.x);
  f16x2 b = __builtin_bit_cast(f16x2, w.y);
  f16x2 c = __builtin_bit_cast(f16x2, w.z);
  f16x2 d = __builtin_bit_cast(f16x2, w.w);
  return (float)a[0]*e[0] + (float)a[1]*e[1] + (float)b[0]*e[2] + (float)b[1]*e[3]
       + (float)c[0]*e[4] + (float)c[1]*e[5] + (float)d[0]*e[6] + (float)d[1]*e[7];
}

__global__ __launch_bounds__(256)
void k_decoder(const f16* __restrict__ dwhh,   // (2,768,256)
               const f16* __restrict__ dwih1,  // (768,256)
               const f16* __restrict__ dwih0,  // (768,8)
               const f16* __restrict__ qw,     // (256,256)
               const f16* __restrict__ outw,   // (29,256)
               const f16* __restrict__ enc,    // (B,512,256)
               const float* __restrict__ dbih, // (2,768)
               const float* __restrict__ dbhh, // (2,768)
               const float* __restrict__ qb, const float* __restrict__ outb,
               const float* __restrict__ emb,  // (29,8)
               const float* __restrict__ hs0, const float* __restrict__ hs1,
               const int* __restrict__ tseq,
               float* __restrict__ out)
{
  const int b = blockIdx.x, tid = threadIdx.x;
  __shared__ __align__(16) f16 h0sh[256], h1sh[256], qsh[256];
  __shared__ float sc[512];
  __shared__ float red[4];
  __shared__ __align__(16) float hc[256];
  __shared__ __align__(16) float cpart[2][256];
  __shared__ float lg[32];
  __shared__ float e8[8];
  __shared__ int toksh;

  // init: h = sum of dir finals; tok = target_seq[:,0]
  h0sh[tid] = (f16)(hs0[b * 256 + tid] + hs0[32768 + b * 256 + tid]);
  h1sh[tid] = (f16)(hs1[b * 256 + tid] + hs1[32768 + b * 256 + tid]);
  if (tid == 0) toksh = tseq[b * 64];
  __syncthreads();

  for (int s = 0; s < NSTEP; ++s) {
    // ---- cell0 ----
    if (tid < 8) e8[tid] = emb[toksh * 8 + tid];
    uint4 wq0 = *(const uint4*)(dwih0 + (size_t)tid * 8);
    uint4 wq1 = *(const uint4*)(dwih0 + (size_t)(tid + 256) * 8);
    uint4 wq2 = *(const uint4*)(dwih0 + (size_t)(tid + 512) * 8);
    float g0 = dbhh[tid], g1 = dbhh[tid + 256], g2 = dbhh[tid + 512];
    mv3(dwhh, tid, (const uint4*)h0sh, g0, g1, g2);
    __syncthreads();             // (A) h0sh reads done; e8 visible
    {
      float i0 = dbih[tid]       + edot(wq0, e8);
      float i1 = dbih[tid + 256] + edot(wq1, e8);
      float i2 = dbih[tid + 512] + edot(wq2, e8);
      float r = sigm_(i0 + g0);
      float z = sigm_(i1 + g1);
      float n = tanhf(i2 + r * g2);
      float hp = (float)h0sh[tid];
      h0sh[tid] = (f16)((1.f - z) * n + z * hp);
    }
    __syncthreads();             // (B) h0sh new visible

    // ---- cell1 ----
    float a0 = dbih[768 + tid], a1 = dbih[768 + tid + 256], a2 = dbih[768 + tid + 512];
    mv3(dwih1, tid, (const uint4*)h0sh, a0, a1, a2);
    float b0 = dbhh[768 + tid], b1 = dbhh[768 + tid + 256], b2 = dbhh[768 + tid + 512];
    mv3(dwhh + (size_t)768 * 256, tid, (const uint4*)h1sh, b0, b1, b2);
    float h1new;
    {
      float r = sigm_(a0 + b0);
      float z = sigm_(a1 + b1);
      float n = tanhf(a2 + r * b2);
      float hp = (float)h1sh[tid];
      h1new = (1.f - z) * n + z * hp;
    }
    __syncthreads();             // (C) h1sh reads done
    h1sh[tid] = (f16)h1new;
    __syncthreads();             // (D)

    // ---- q = qW @ h1' + qb ----
    qsh[tid] = (f16)mv1(qw, tid, (const uint4*)h1sh, qb[tid]);
    __syncthreads();             // (E)

    // ---- scores ----
#pragma unroll
    for (int pass = 0; pass < 2; ++pass) {
      int t = tid + pass * 256;
      sc[t] = mv1(enc, (size_t)b * 512 + t, (const uint4*)qsh, 0.f);
    }
    __syncthreads();             // (F)

    // ---- softmax ----
    float mloc = fmaxf(sc[tid], sc[tid + 256]);
#pragma unroll
    for (int off = 32; off; off >>= 1) mloc = fmaxf(mloc, __shfl_xor(mloc, off));
    if ((tid & 63) == 0) red[tid >> 6] = mloc;
    __syncthreads();
    float m = fmaxf(fmaxf(red[0], red[1]), fmaxf(red[2], red[3]));
    float ex0 = __expf(sc[tid] - m), ex1 = __expf(sc[tid + 256] - m);
    __syncthreads();             // red reads done before reuse
    sc[tid] = ex0; sc[tid + 256] = ex1;
    float lloc = ex0 + ex1;
#pragma unroll
    for (int off = 32; off; off >>= 1) lloc += __shfl_xor(lloc, off);
    if ((tid & 63) == 0) red[tid >> 6] = lloc;
    __syncthreads();
    float l = red[0] + red[1] + red[2] + red[3];

    // ---- ctx: thread (c2=tid&127, th=tid>>7) accumulates channels 2c2,2c2+1
    {
      const int c2 = tid & 127, th = tid >> 7;
      const uint32_t* eb = (const uint32_t*)enc + (((size_t)b * 512 + th * 256) * 128) + c2;
      const float* wsc = sc + th * 256;
      float c0 = 0.f, c1 = 0.f;
#pragma unroll 8
      for (int i = 0; i < 256; ++i) {
        uint32_t v = eb[(size_t)i * 128];
        float wgt = wsc[i];
        f16x2 h2 = __builtin_bit_cast(f16x2, v);
        c0 += wgt * (float)h2[0];
        c1 += wgt * (float)h2[1];
      }
      ((float2*)cpart[th])[c2] = float2{c0, c1};
    }
    __syncthreads();
    hc[tid] = (cpart[0][tid] + cpart[1][tid]) / l + (float)h1sh[tid];
    __syncthreads();

    // ---- logits (29x256) + argmax ----
    if (tid < VV * 8) {
      const int v = tid >> 3, kseg = tid & 7;
      float acc = 0.f;
      const uint4* ow = (const uint4*)(outw + (size_t)v * 256 + kseg * 32);
      const float4* hv = (const float4*)(hc + kseg * 32);
#pragma unroll
      for (int j = 0; j < 4; ++j) {
        uint4 wq = ow[j];
        float4 ha = hv[2 * j], hb = hv[2 * j + 1];
        f16x2 p0 = __builtin_bit_cast(f16x2, wq.x);
        f16x2 p1 = __builtin_bit_cast(f16x2, wq.y);
        f16x2 p2 = __builtin_bit_cast(f16x2, wq.z);
        f16x2 p3 = __builtin_bit_cast(f16x2, wq.w);
        acc += (float)p0[0]*ha.x + (float)p0[1]*ha.y + (float)p1[0]*ha.z + (float)p1[1]*ha.w;
        acc += (float)p2[0]*hb.x + (float)p2[1]*hb.y + (float)p3[0]*hb.z + (float)p3[1]*hb.w;
      }
      acc += __shfl_xor(acc, 1);
      acc += __shfl_xor(acc, 2);
      acc += __shfl_xor(acc, 4);
      if (kseg == 0) {
        float lv = acc + outb[v];
        lg[v] = lv;
        out[((size_t)b * NSTEP + s) * VV + v] = lv;
      }
    }
    __syncthreads();
    if (tid == 0) {
      int best = 0; float bv = lg[0];
      for (int v = 1; v < VV; ++v) if (lg[v] > bv) { bv = lg[v]; best = v; }
      toksh = best;
    }
    __syncthreads();
  }

  // final hidden: out[233856 + {0,1}*32768 + b*256 + p]
  out[233856 + b * 256 + tid] = (float)h0sh[tid];
  out[233856 + 32768 + b * 256 + tid] = (float)h1sh[tid];
}

extern "C" void kernel_launch(void* const* d_in, const int* in_sizes, int n_in,
                              void* d_out, int out_size, void* d_ws, size_t ws_size,
                              hipStream_t stream) {
  (void)in_sizes; (void)n_in; (void)out_size; (void)ws_size;
  const float* x     = (const float*)d_in[0];
  const int*   tseq  = (const int*)d_in[1];
  const float* eWih0 = (const float*)d_in[2];
  const float* eWhh0 = (const float*)d_in[3];
  const float* ebih0 = (const float*)d_in[4];
  const float* ebhh0 = (const float*)d_in[5];
  const float* eWih1 = (const float*)d_in[6];
  const float* eWhh1 = (const float*)d_in[7];
  const float* ebih1 = (const float*)d_in[8];
  const float* ebhh1 = (const float*)d_in[9];
  const float* e2dW  = (const float*)d_in[10];
  const float* e2db  = (const float*)d_in[11];
  const float* dWih0 = (const float*)d_in[12];
  const float* dWih1 = (const float*)d_in[13];
  const float* dWhh  = (const float*)d_in[14];
  const float* dbih  = (const float*)d_in[15];
  const float* dbhh  = (const float*)d_in[16];
  const float* qW    = (const float*)d_in[17];
  const float* qb    = (const float*)d_in[18];
  const float* outW  = (const float*)d_in[19];
  const float* outb  = (const float*)d_in[20];
  const float* emb   = (const float*)d_in[21];

  // ---- workspace ledger (peak ~166 MB) ----
  uint8_t* ws = (uint8_t*)d_ws;
  size_t o = 0;
  auto take = [&](size_t bytes) -> void* {
    void* p = ws + o;
    o += (bytes + 255) & ~(size_t)255;
    return p;
  };
  f16* whh0_16  = (f16*)take((size_t)2 * 768 * 256 * 2);
  f16* whh1_16  = (f16*)take((size_t)2 * 768 * 256 * 2);
  f16* wih1_16  = (f16*)take((size_t)2 * 768 * 512 * 2);
  f16* e2d_16   = (f16*)take((size_t)256 * 512 * 2);
  f16* qw_16    = (f16*)take((size_t)256 * 256 * 2);
  f16* outw_16  = (f16*)take((size_t)29 * 256 * 2);
  f16* dwih0_16 = (f16*)take((size_t)768 * 8 * 2);
  f16* dwih1_16 = (f16*)take((size_t)768 * 256 * 2);
  f16* dwhh_16  = (f16*)take((size_t)2 * 768 * 256 * 2);
  f16* y0   = (f16*)take((size_t)BT * 512 * 2);          // enc aliases later
  f16* y1   = (f16*)take((size_t)BT * 512 * 2);
  f16* gi   = (f16*)take((size_t)BB * CHUNK * 1536 * 2); // rolling chunk
  float* hs0 = (float*)take((size_t)2 * BB * 256 * 4);
  float* hs1 = (float*)take((size_t)2 * BB * 256 * 4);
  f16* enc = y0;  // alias: y0 dead after last gi chunk GEMM

  hipMemsetAsync(hs0, 0, (size_t)2 * BB * 256 * 4, stream);
  hipMemsetAsync(hs1, 0, (size_t)2 * BB * 256 * 4, stream);

  auto cvt = [&](const float* s, f16* d, int n) {
    k_cvt<<<(n + 255) / 256, 256, 0, stream>>>(s, d, n);
  };
  cvt(eWhh0, whh0_16, 2 * 768 * 256);
  cvt(eWhh1, whh1_16, 2 * 768 * 256);
  cvt(eWih1, wih1_16, 2 * 768 * 512);
  cvt(e2dW,  e2d_16,  256 * 512);
  cvt(qW,    qw_16,   256 * 256);
  cvt(outW,  outw_16, 29 * 256);
  cvt(dWih0, dwih0_16, 768 * 8);
  cvt(dWih1, dwih1_16, 768 * 256);
  cvt(dWhh,  dwhh_16, 2 * 768 * 256);

  // encoder layer 0 (both dirs, full T; gi inline since IN=2)
  k_scan<0><<<256, 512, 0, stream>>>(x, nullptr, (const uint32_t*)whh0_16,
                                     eWih0, ebih0, ebhh0, y0, hs0, 0, TT);

  // encoder layer 1: time-chunked gi GEMM + scan
  const long BSTR = (long)TT * 512;  // per-b element stride in y0
  for (int c = 0; c < TT / CHUNK; ++c) {
    const int t0 = c * CHUNK;
    k_gemm<<<dim3(BB * CHUNK / 64, 12), 256, 0, stream>>>(
        y0 + (size_t)t0 * 512, wih1_16, gi, ebih1,
        512, 6, BSTR, 512, 1536, 0);
    k_gemm<<<dim3(BB * CHUNK / 64, 12), 256, 0, stream>>>(
        y0 + (size_t)(TT - 1 - t0) * 512, wih1_16 + (size_t)768 * 512, gi, ebih1 + 768,
        512, 6, BSTR, -512, 1536, 768);
    k_scan<1><<<256, 512, 0, stream>>>(nullptr, gi, (const uint32_t*)whh1_16,
                                       nullptr, nullptr, ebhh1, y1, hs1, t0, CHUNK);
  }

  // enc = y1 @ e2d^T + b   (writes into y0's region)
  k_gemm<<<dim3(BT / 64, 4), 256, 0, stream>>>(y1, e2d_16, enc, e2db,
                                               512, 30, 0, 512, 256, 0);

  // persistent decoder: one WG per batch element, all 63 steps
  k_decoder<<<128, 256, 0, stream>>>(dwhh_16, dwih1_16, dwih0_16, qw_16, outw_16,
                                     enc, dbih, dbhh, qb, outb, emb,
                                     hs0, hs1, tseq, (float*)d_out);
}